// Round 1
// baseline (1523.842 us; speedup 1.0000x reference)
//
#include <hip/hip_runtime.h>

#define EPS 1e-5f
#define SLOPE 0.01f

__device__ __forceinline__ float leaky(float z) { return z >= 0.f ? z : SLOPE * z; }

// u[n][c] = b1a[c] + sum_k x[n][k] * W1a[k][c]   (top 64 rows of W1a)
__global__ __launch_bounds__(128) void k_u(const float* __restrict__ x,
                                           const float* __restrict__ W1a,
                                           const float* __restrict__ b1a,
                                           float* __restrict__ u, int N) {
    const int c = threadIdx.x;  // channel 0..127
    float Wreg[64];
#pragma unroll
    for (int k = 0; k < 64; ++k) Wreg[k] = W1a[k * 128 + c];
    const float bc = b1a[c];
    int n0 = blockIdx.x * 64;
    int n1 = min(n0 + 64, N);
    for (int n = n0; n < n1; ++n) {
        const float* xr = x + (size_t)n * 64;  // n is uniform -> s_load path
        float acc = bc;
#pragma unroll
        for (int k = 0; k < 64; ++k) acc = fmaf(xr[k], Wreg[k], acc);
        u[(size_t)n * 128 + c] = acc;
    }
}

// gdst[e] = batch[col[e]], histogram counts[g]
__global__ void k_prep(const int* __restrict__ ei, const int* __restrict__ batch,
                       int* __restrict__ gdst, int* __restrict__ counts, int E) {
    int t = blockIdx.x * blockDim.x + threadIdx.x;
    if (t < E) {
        int c = ei[E + t];  // col
        int g = batch[c];
        gdst[t] = g;
        atomicAdd(&counts[g], 1);
    }
}

// node_off[g] = first node index with batch >= g (batch is sorted); node_off[B]=N
__global__ void k_nodeoff(const int* __restrict__ batch, int* __restrict__ node_off,
                          int N, int B) {
    int n = blockIdx.x * blockDim.x + threadIdx.x;
    if (n >= N) return;
    int b1 = batch[n];
    int prev = (n == 0) ? -1 : batch[n - 1];
    for (int g = prev + 1; g <= b1; ++g) node_off[g] = n;
    if (n == N - 1) {
        for (int g = b1 + 1; g <= B; ++g) node_off[g] = N;
    }
}

// exclusive scan of counts -> edge_off[0..B]; cursor = edge_off[0..B-1]
__global__ void k_scan(const int* __restrict__ counts, int* __restrict__ edge_off,
                       int* __restrict__ cursor, int B) {
    __shared__ int s[1024];
    int t = threadIdx.x;
    s[t] = (t < B) ? counts[t] : 0;
    __syncthreads();
    for (int d = 1; d < 1024; d <<= 1) {
        int v = (t >= d) ? s[t - d] : 0;
        __syncthreads();
        s[t] += v;
        __syncthreads();
    }
    if (t <= B) {
        int excl = (t == 0) ? 0 : s[t - 1];
        edge_off[t] = excl;
        if (t < B) cursor[t] = excl;
    }
}

// perm: edge ids grouped by destination graph
__global__ void k_scatter(const int* __restrict__ gdst, int* __restrict__ cursor,
                          int* __restrict__ perm, int E) {
    int t = blockIdx.x * blockDim.x + threadIdx.x;
    if (t < E) {
        int g = gdst[t];
        int pos = atomicAdd(&cursor[g], 1);
        perm[pos] = t;
    }
}

// gx[g][l] = sum over nodes of graph g of x[n][l]
__global__ __launch_bounds__(64) void k_gx(const float* __restrict__ x,
                                           const int* __restrict__ node_off,
                                           float* __restrict__ gx, int B) {
    int g = blockIdx.x, l = threadIdx.x;
    int n0 = node_off[g], n1 = node_off[g + 1];
    float acc = 0.f;
    for (int n = n0; n < n1; ++n) acc += x[(size_t)n * 64 + l];
    gx[g * 64 + l] = acc;
}

// Heavy kernel: per edge a = leaky(u[row] + ea @ W1a_bot); accumulate per-graph
// S_g (sum a) and Q_g (sum a^2) in registers, flush with atomics.
__global__ __launch_bounds__(256) void k_edges(
    const float* __restrict__ edge_attr, const float* __restrict__ u,
    const int* __restrict__ ei, const int* __restrict__ perm,
    const int* __restrict__ edge_off, const float* __restrict__ W1a,
    float* __restrict__ Sg, float* __restrict__ Qg, int CH) {
    int g = blockIdx.x;  // graph
    int j = blockIdx.y;  // chunk
    int c = threadIdx.x & 127;
    int half = threadIdx.x >> 7;  // wave-uniform (waves 0,1 -> 0; waves 2,3 -> 1)
    float Wreg[64];
#pragma unroll
    for (int k = 0; k < 64; ++k) Wreg[k] = W1a[(64 + k) * 128 + c];
    int e0 = edge_off[g], e1 = edge_off[g + 1];
    int cnt = e1 - e0;
    int chunk = (cnt + CH - 1) / CH;
    int lo = e0 + j * chunk;
    int hi = min(lo + chunk, e1);
    float accS = 0.f, accQ = 0.f;
    for (int i = lo + half; i < hi; i += 2) {
        int e = __builtin_amdgcn_readfirstlane(perm[i]);  // wave-uniform edge id
        int r = __builtin_amdgcn_readfirstlane(ei[e]);    // row (source node)
        const float* ea = edge_attr + (size_t)e * 64;     // uniform -> s_load
        float pre = u[(size_t)r * 128 + c];
#pragma unroll
        for (int k = 0; k < 64; ++k) pre = fmaf(ea[k], Wreg[k], pre);
        float a = leaky(pre);
        accS += a;
        accQ += a * a;
    }
    atomicAdd(&Sg[g * 128 + c], accS);
    atomicAdd(&Qg[g * 128 + c], accQ);
}

// Fold edge-BN stats: scale/shift per channel
__global__ __launch_bounds__(128) void k_stats(const float* __restrict__ Sg,
                                               const float* __restrict__ Qg,
                                               const float* __restrict__ g1a,
                                               const float* __restrict__ be1a,
                                               float* __restrict__ scale_a,
                                               float* __restrict__ shift_a, int B,
                                               float invE) {
    int c = threadIdx.x;
    float S = 0.f, Q = 0.f;
    for (int g = 0; g < B; ++g) {
        S += Sg[g * 128 + c];
        Q += Qg[g * 128 + c];
    }
    float m = S * invE;
    float v = Q * invE - m * m;
    float sc = g1a[c] * rsqrtf(v + EPS);
    scale_a[c] = sc;
    shift_a[c] = be1a[c] - m * sc;
}

// Per graph: T = S_g*scale + c_g*shift; ga = T@W2a + c_g*b2a;
// gcat=[gx,ga]; a1 = leaky(gcat@W1b + b1b); accumulate BN1b stats.
__global__ __launch_bounds__(128) void k_g1(
    const float* __restrict__ Sg, const float* __restrict__ gx,
    const int* __restrict__ edge_off, const float* __restrict__ scale_a,
    const float* __restrict__ shift_a, const float* __restrict__ W2a,
    const float* __restrict__ b2a, const float* __restrict__ W1b,
    const float* __restrict__ b1b, float* __restrict__ a1,
    float* __restrict__ sum1, float* __restrict__ sumsq1) {
    __shared__ float T[128];
    __shared__ float gcat[192];
    int g = blockIdx.x, c = threadIdx.x;
    float cg = (float)(edge_off[g + 1] - edge_off[g]);
    T[c] = Sg[g * 128 + c] * scale_a[c] + cg * shift_a[c];
    if (c < 64) gcat[c] = gx[g * 64 + c];
    __syncthreads();
    float ga = cg * b2a[c];
#pragma unroll 8
    for (int k = 0; k < 128; ++k) ga = fmaf(T[k], W2a[k * 128 + c], ga);
    gcat[64 + c] = ga;
    __syncthreads();
    float z = b1b[c];
#pragma unroll 8
    for (int k = 0; k < 192; ++k) z = fmaf(gcat[k], W1b[k * 128 + c], z);
    float av = leaky(z);
    a1[g * 128 + c] = av;
    atomicAdd(&sum1[c], av);
    atomicAdd(&sumsq1[c], av * av);
}

// hnorm = BN(a_prev) (stats from sum/sumsq over B rows); z = hnorm@W + b;
// optionally leaky + accumulate next stats; write a_out.
__global__ __launch_bounds__(128) void k_bn_lin(
    const float* __restrict__ a_prev, const float* __restrict__ sum,
    const float* __restrict__ sumsq, const float* __restrict__ gma,
    const float* __restrict__ bta, const float* __restrict__ W,
    const float* __restrict__ b, float* __restrict__ a_out,
    float* __restrict__ sum_out, float* __restrict__ sumsq_out, float invB,
    int do_leaky) {
    __shared__ float hs[128];
    int g = blockIdx.x, c = threadIdx.x;
    float m = sum[c] * invB;
    float v = sumsq[c] * invB - m * m;
    float sc = gma[c] * rsqrtf(v + EPS);
    float sh = bta[c] - m * sc;
    hs[c] = a_prev[g * 128 + c] * sc + sh;
    __syncthreads();
    float z = b[c];
#pragma unroll 8
    for (int k = 0; k < 128; ++k) z = fmaf(hs[k], W[k * 128 + c], z);
    if (do_leaky) {
        z = leaky(z);
        a_out[g * 128 + c] = z;
        atomicAdd(&sum_out[c], z);
        atomicAdd(&sumsq_out[c], z * z);
    } else {
        a_out[g * 128 + c] = z;
    }
}

extern "C" void kernel_launch(void* const* d_in, const int* in_sizes, int n_in,
                              void* d_out, int out_size, void* d_ws, size_t ws_size,
                              hipStream_t stream) {
    const float* x    = (const float*)d_in[0];
    const int*   ei   = (const int*)d_in[1];
    const float* ea   = (const float*)d_in[2];
    const int*   batch= (const int*)d_in[4];
    const float* W1a  = (const float*)d_in[5];
    const float* b1a  = (const float*)d_in[6];
    const float* g1a  = (const float*)d_in[7];
    const float* be1a = (const float*)d_in[8];
    const float* W2a  = (const float*)d_in[9];
    const float* b2a  = (const float*)d_in[10];
    const float* W1b  = (const float*)d_in[11];
    const float* b1b  = (const float*)d_in[12];
    const float* g1b  = (const float*)d_in[13];
    const float* be1b = (const float*)d_in[14];
    const float* W2b  = (const float*)d_in[15];
    const float* b2b  = (const float*)d_in[16];
    const float* g2b  = (const float*)d_in[17];
    const float* be2b = (const float*)d_in[18];
    const float* W3b  = (const float*)d_in[19];
    const float* b3b  = (const float*)d_in[20];

    const int N = in_sizes[0] / 64;
    const int E = in_sizes[1] / 2;
    const int B = in_sizes[3];

    char* ws = (char*)d_ws;
    size_t off = 0;
    auto alloc = [&](size_t bytes) -> char* {
        char* p = ws + off;
        off = (off + bytes + 255) & ~(size_t)255;
        return p;
    };
    // ---- zeroed region (one memset) ----
    int*   counts = (int*)alloc((size_t)B * 4);
    float* Sg     = (float*)alloc((size_t)B * 128 * 4);
    float* Qg     = (float*)alloc((size_t)B * 128 * 4);
    float* sum1   = (float*)alloc(128 * 4);
    float* sumsq1 = (float*)alloc(128 * 4);
    float* sum2   = (float*)alloc(128 * 4);
    float* sumsq2 = (float*)alloc(128 * 4);
    size_t zbytes = off;
    // ---- non-zeroed scratch ----
    float* u       = (float*)alloc((size_t)N * 128 * 4);
    int*   gdst    = (int*)alloc((size_t)E * 4);
    int*   perm    = (int*)alloc((size_t)E * 4);
    int*   edge_off= (int*)alloc((size_t)(B + 1) * 4);
    int*   cursor  = (int*)alloc((size_t)B * 4);
    int*   node_off= (int*)alloc((size_t)(B + 1) * 4);
    float* gx      = (float*)alloc((size_t)B * 64 * 4);
    float* a1      = (float*)alloc((size_t)B * 128 * 4);
    float* a2      = (float*)alloc((size_t)B * 128 * 4);
    float* scale_a = (float*)alloc(128 * 4);
    float* shift_a = (float*)alloc(128 * 4);
    (void)ws_size;
    (void)n_in;

    hipMemsetAsync(ws, 0, zbytes, stream);

    k_u<<<dim3((N + 63) / 64), dim3(128), 0, stream>>>(x, W1a, b1a, u, N);
    k_prep<<<dim3((E + 255) / 256), dim3(256), 0, stream>>>(ei, batch, gdst, counts, E);
    k_nodeoff<<<dim3((N + 255) / 256), dim3(256), 0, stream>>>(batch, node_off, N, B);
    k_scan<<<dim3(1), dim3(1024), 0, stream>>>(counts, edge_off, cursor, B);
    k_scatter<<<dim3((E + 255) / 256), dim3(256), 0, stream>>>(gdst, cursor, perm, E);
    k_gx<<<dim3(B), dim3(64), 0, stream>>>(x, node_off, gx, B);

    const int CH = 8;  // chunks per graph
    k_edges<<<dim3(B, CH), dim3(256), 0, stream>>>(ea, u, ei, perm, edge_off, W1a,
                                                   Sg, Qg, CH);

    k_stats<<<dim3(1), dim3(128), 0, stream>>>(Sg, Qg, g1a, be1a, scale_a, shift_a,
                                               B, 1.0f / (float)E);
    k_g1<<<dim3(B), dim3(128), 0, stream>>>(Sg, gx, edge_off, scale_a, shift_a, W2a,
                                            b2a, W1b, b1b, a1, sum1, sumsq1);
    k_bn_lin<<<dim3(B), dim3(128), 0, stream>>>(a1, sum1, sumsq1, g1b, be1b, W2b,
                                                b2b, a2, sum2, sumsq2,
                                                1.0f / (float)B, 1);
    k_bn_lin<<<dim3(B), dim3(128), 0, stream>>>(a2, sum2, sumsq2, g2b, be2b, W3b,
                                                b3b, (float*)d_out, nullptr, nullptr,
                                                1.0f / (float)B, 0);
}

// Round 2
// 616.687 us; speedup vs baseline: 2.4710x; 2.4710x over previous
//
#include <hip/hip_runtime.h>

#define EPS 1e-5f
#define SLOPE 0.01f
#define NB 500  // upper bound on batch count B used for LDS bins (B=500 here)

typedef __attribute__((ext_vector_type(8))) short bf16x8;
typedef __attribute__((ext_vector_type(4))) float f32x4;

__device__ __forceinline__ float leaky(float z) { return z >= 0.f ? z : SLOPE * z; }

// float -> bf16 bits, round-nearest-even
__device__ __forceinline__ short f2bf(float f) {
    unsigned u = __float_as_uint(f);
    u += 0x7fff + ((u >> 16) & 1);
    return (short)(u >> 16);
}

// u[n][c] = b1a[c] + sum_k x[n][k] * W1a[k][c]   (top 64 rows of W1a)
__global__ __launch_bounds__(128) void k_u(const float* __restrict__ x,
                                           const float* __restrict__ W1a,
                                           const float* __restrict__ b1a,
                                           float* __restrict__ u, int N) {
    const int c = threadIdx.x;
    float Wreg[64];
#pragma unroll
    for (int k = 0; k < 64; ++k) Wreg[k] = W1a[k * 128 + c];
    const float bc = b1a[c];
    int n0 = blockIdx.x * 64;
    int n1 = min(n0 + 64, N);
    for (int n = n0; n < n1; n += 2) {
        const float* x0 = x + (size_t)n * 64;
        bool two = (n + 1 < n1);
        const float* x1 = two ? x0 + 64 : x0;
        float a0 = bc, a1 = bc;
#pragma unroll
        for (int k = 0; k < 64; ++k) {
            a0 = fmaf(x0[k], Wreg[k], a0);
            a1 = fmaf(x1[k], Wreg[k], a1);
        }
        u[(size_t)n * 128 + c] = a0;
        if (two) u[(size_t)(n + 1) * 128 + c] = a1;
    }
}

// Block-local histogram (4096 edges/block) -> LDS, then <=NB global atomics/block.
// Also materializes gdst[e] = batch[col[e]].
__global__ __launch_bounds__(256) void k_hist(const int* __restrict__ ei,
                                              const int* __restrict__ batch,
                                              int* __restrict__ gdst,
                                              int* __restrict__ counts, int E) {
    __shared__ int h[NB];
    int t = threadIdx.x;
    for (int b = t; b < NB; b += 256) h[b] = 0;
    __syncthreads();
    int base = blockIdx.x * 4096;
#pragma unroll
    for (int i = 0; i < 16; ++i) {
        int e = base + i * 256 + t;
        if (e < E) {
            int g = batch[ei[E + e]];
            gdst[e] = g;
            atomicAdd(&h[g], 1);
        }
    }
    __syncthreads();
    for (int b = t; b < NB; b += 256)
        if (h[b]) atomicAdd(&counts[b], h[b]);
}

// node_off[g] = first node index with batch >= g (batch sorted); node_off[B]=N
__global__ void k_nodeoff(const int* __restrict__ batch, int* __restrict__ node_off,
                          int N, int B) {
    int n = blockIdx.x * blockDim.x + threadIdx.x;
    if (n >= N) return;
    int b1 = batch[n];
    int prev = (n == 0) ? -1 : batch[n - 1];
    for (int g = prev + 1; g <= b1; ++g) node_off[g] = n;
    if (n == N - 1)
        for (int g = b1 + 1; g <= B; ++g) node_off[g] = N;
}

// exclusive scan of counts -> edge_off[0..B]; cursor = edge_off[0..B-1]
__global__ void k_scan(const int* __restrict__ counts, int* __restrict__ edge_off,
                       int* __restrict__ cursor, int B) {
    __shared__ int s[1024];
    int t = threadIdx.x;
    s[t] = (t < B) ? counts[t] : 0;
    __syncthreads();
    for (int d = 1; d < 1024; d <<= 1) {
        int v = (t >= d) ? s[t - d] : 0;
        __syncthreads();
        s[t] += v;
        __syncthreads();
    }
    if (t <= B) {
        int excl = (t == 0) ? 0 : s[t - 1];
        edge_off[t] = excl;
        if (t < B) cursor[t] = excl;
    }
}

// Block-local counting-sort scatter: LDS hist -> one reserve atomic per
// (block,bin) -> LDS-ranked scatter. Order within a bin is arbitrary (sums
// are order-invariant up to fp rounding; threshold has ample slack).
__global__ __launch_bounds__(256) void k_scat(const int* __restrict__ gdst,
                                              int* __restrict__ cursor,
                                              int* __restrict__ perm, int E) {
    __shared__ int cnt[NB];
    __shared__ int base[NB];
    int t = threadIdx.x;
    for (int b = t; b < NB; b += 256) cnt[b] = 0;
    __syncthreads();
    int blk = blockIdx.x * 4096;
    int g[16];
#pragma unroll
    for (int i = 0; i < 16; ++i) {
        int e = blk + i * 256 + t;
        g[i] = (e < E) ? gdst[e] : -1;
        if (g[i] >= 0) atomicAdd(&cnt[g[i]], 1);
    }
    __syncthreads();
    for (int b = t; b < NB; b += 256) {
        int c = cnt[b];
        base[b] = c ? atomicAdd(&cursor[b], c) : 0;
    }
    __syncthreads();
    for (int b = t; b < NB; b += 256) cnt[b] = 0;
    __syncthreads();
#pragma unroll
    for (int i = 0; i < 16; ++i) {
        int e = blk + i * 256 + t;
        if (g[i] >= 0) {
            int r = atomicAdd(&cnt[g[i]], 1);
            perm[base[g[i]] + r] = e;
        }
    }
}

// gx[g][l] = sum over nodes of graph g of x[n][l]
__global__ __launch_bounds__(64) void k_gx(const float* __restrict__ x,
                                           const int* __restrict__ node_off,
                                           float* __restrict__ gx, int B) {
    int g = blockIdx.x, l = threadIdx.x;
    int n0 = node_off[g], n1 = node_off[g + 1];
    float a0 = 0.f, a1 = 0.f;
    int n = n0;
    for (; n + 1 < n1; n += 2) {
        a0 += x[(size_t)n * 64 + l];
        a1 += x[(size_t)(n + 1) * 64 + l];
    }
    if (n < n1) a0 += x[(size_t)n * 64 + l];
    gx[g * 64 + l] = a0 + a1;
}

// MFMA edge kernel. Per wave-iteration: 16 edges x 128 channels.
//   pre = u[row[e]] (fp32, loaded into the C operand) + ea[e] @ W1a_bot (bf16 MFMA)
//   a = leaky(pre); accumulate per-graph sum/sumsq in registers, flush once.
// Fragment layouts (measured, m89/m120): A[m=lane&15][k=quad*8+j],
// B[k=quad*8+j][n=lane&15], C/D col=lane&15, row=quad*4+reg.
__global__ __launch_bounds__(256) void k_edges(
    const float* __restrict__ ea, const float* __restrict__ u,
    const int* __restrict__ ei, const int* __restrict__ perm,
    const int* __restrict__ edge_off, const float* __restrict__ W1a,
    float* __restrict__ Sg, float* __restrict__ Qg, int CH) {
    const int g = blockIdx.x;
    const int lane = threadIdx.x & 63;
    const int wave = threadIdx.x >> 6;
    const int m = lane & 15;   // edge slot (A) / channel-within-tile (B, C/D)
    const int quad = lane >> 4;

    // Preload W1a_bot fragments: 8 channel-tiles x 2 K-steps, bf16.
    bf16x8 Wf[8][2];
#pragma unroll
    for (int t = 0; t < 8; ++t)
#pragma unroll
        for (int kh = 0; kh < 2; ++kh)
#pragma unroll
            for (int j = 0; j < 8; ++j)
                Wf[t][kh][j] = f2bf(W1a[(64 + kh * 32 + quad * 8 + j) * 128 + t * 16 + m]);

    const int e0 = edge_off[g], e1 = edge_off[g + 1];
    const int cnt = e1 - e0;
    const int chunk = (cnt + CH - 1) / CH;
    const int lo = e0 + blockIdx.y * chunk;
    const int hi = min(lo + chunk, e1);

    float accS[8] = {0, 0, 0, 0, 0, 0, 0, 0};
    float accQ[8] = {0, 0, 0, 0, 0, 0, 0, 0};

    for (int ib = lo + wave * 16; ib < hi; ib += 64) {
        int idx = min(ib + m, hi - 1);   // clamp tail (masked in epilogue)
        int e = perm[idx];
        int rid = ei[e];                 // source node of slot-m edge
        // A fragments: 8 fp32 -> bf16 per K-half
        const float* ar = ea + (size_t)e * 64;
        bf16x8 A[2];
#pragma unroll
        for (int kh = 0; kh < 2; ++kh) {
            f32x4 p0 = *(const f32x4*)(ar + kh * 32 + quad * 8);
            f32x4 p1 = *(const f32x4*)(ar + kh * 32 + quad * 8 + 4);
#pragma unroll
            for (int j = 0; j < 4; ++j) {
                A[kh][j] = f2bf(p0[j]);
                A[kh][4 + j] = f2bf(p1[j]);
            }
        }
        // rows + validity for the 4 D-rows this lane covers (m' = quad*4+r)
        int r0 = __shfl(rid, quad * 4 + 0);
        int r1 = __shfl(rid, quad * 4 + 1);
        int r2 = __shfl(rid, quad * 4 + 2);
        int r3 = __shfl(rid, quad * 4 + 3);
        bool v0 = (ib + quad * 4 + 0) < hi;
        bool v1 = (ib + quad * 4 + 1) < hi;
        bool v2 = (ib + quad * 4 + 2) < hi;
        bool v3 = (ib + quad * 4 + 3) < hi;
#pragma unroll
        for (int t = 0; t < 8; ++t) {
            f32x4 c;
            c[0] = u[(size_t)r0 * 128 + t * 16 + m];
            c[1] = u[(size_t)r1 * 128 + t * 16 + m];
            c[2] = u[(size_t)r2 * 128 + t * 16 + m];
            c[3] = u[(size_t)r3 * 128 + t * 16 + m];
            c = __builtin_amdgcn_mfma_f32_16x16x32_bf16(A[0], Wf[t][0], c, 0, 0, 0);
            c = __builtin_amdgcn_mfma_f32_16x16x32_bf16(A[1], Wf[t][1], c, 0, 0, 0);
            float a0 = v0 ? leaky(c[0]) : 0.f;
            float a1 = v1 ? leaky(c[1]) : 0.f;
            float a2 = v2 ? leaky(c[2]) : 0.f;
            float a3 = v3 ? leaky(c[3]) : 0.f;
            accS[t] += (a0 + a1) + (a2 + a3);
            accQ[t] += (a0 * a0 + a1 * a1) + (a2 * a2 + a3 * a3);
        }
    }
    // cross-quad reduction (16 edges per wave-iter live across 4 quads), flush
#pragma unroll
    for (int t = 0; t < 8; ++t) {
        float s = accS[t];
        s += __shfl_xor(s, 16);
        s += __shfl_xor(s, 32);
        float q = accQ[t];
        q += __shfl_xor(q, 16);
        q += __shfl_xor(q, 32);
        if (quad == 0) {
            atomicAdd(&Sg[g * 128 + t * 16 + m], s);
            atomicAdd(&Qg[g * 128 + t * 16 + m], q);
        }
    }
}

// Partial reduction of Sg/Qg over graphs -> Stot/Qtot (parallel across 25 blocks)
__global__ __launch_bounds__(128) void k_stats_part(const float* __restrict__ Sg,
                                                    const float* __restrict__ Qg,
                                                    float* __restrict__ Stot,
                                                    float* __restrict__ Qtot, int B) {
    int c = threadIdx.x;
    int per = (B + gridDim.x - 1) / gridDim.x;
    int g0 = blockIdx.x * per, g1 = min(g0 + per, B);
    float S = 0.f, Q = 0.f;
    for (int g = g0; g < g1; ++g) {
        S += Sg[g * 128 + c];
        Q += Qg[g * 128 + c];
    }
    atomicAdd(&Stot[c], S);
    atomicAdd(&Qtot[c], Q);
}

__global__ __launch_bounds__(128) void k_stats_fin(const float* __restrict__ Stot,
                                                   const float* __restrict__ Qtot,
                                                   const float* __restrict__ g1a,
                                                   const float* __restrict__ be1a,
                                                   float* __restrict__ scale_a,
                                                   float* __restrict__ shift_a,
                                                   float invE) {
    int c = threadIdx.x;
    float mn = Stot[c] * invE;
    float v = Qtot[c] * invE - mn * mn;
    float sc = g1a[c] * rsqrtf(v + EPS);
    scale_a[c] = sc;
    shift_a[c] = be1a[c] - mn * sc;
}

// Per graph: T = S_g*scale + c_g*shift; ga = T@W2a + c_g*b2a;
// gcat=[gx,ga]; a1 = leaky(gcat@W1b + b1b); accumulate BN1b stats.
__global__ __launch_bounds__(128) void k_g1(
    const float* __restrict__ Sg, const float* __restrict__ gx,
    const int* __restrict__ edge_off, const float* __restrict__ scale_a,
    const float* __restrict__ shift_a, const float* __restrict__ W2a,
    const float* __restrict__ b2a, const float* __restrict__ W1b,
    const float* __restrict__ b1b, float* __restrict__ a1,
    float* __restrict__ sum1, float* __restrict__ sumsq1) {
    __shared__ float T[128];
    __shared__ float gcat[192];
    int g = blockIdx.x, c = threadIdx.x;
    float cg = (float)(edge_off[g + 1] - edge_off[g]);
    T[c] = Sg[g * 128 + c] * scale_a[c] + cg * shift_a[c];
    if (c < 64) gcat[c] = gx[g * 64 + c];
    __syncthreads();
    float ga = cg * b2a[c];
#pragma unroll 8
    for (int k = 0; k < 128; ++k) ga = fmaf(T[k], W2a[k * 128 + c], ga);
    gcat[64 + c] = ga;
    __syncthreads();
    float z = b1b[c];
#pragma unroll 8
    for (int k = 0; k < 192; ++k) z = fmaf(gcat[k], W1b[k * 128 + c], z);
    float av = leaky(z);
    a1[g * 128 + c] = av;
    atomicAdd(&sum1[c], av);
    atomicAdd(&sumsq1[c], av * av);
}

// hnorm = BN(a_prev); z = hnorm@W + b; optional leaky + next-stats.
__global__ __launch_bounds__(128) void k_bn_lin(
    const float* __restrict__ a_prev, const float* __restrict__ sum,
    const float* __restrict__ sumsq, const float* __restrict__ gma,
    const float* __restrict__ bta, const float* __restrict__ W,
    const float* __restrict__ b, float* __restrict__ a_out,
    float* __restrict__ sum_out, float* __restrict__ sumsq_out, float invB,
    int do_leaky) {
    __shared__ float hs[128];
    int g = blockIdx.x, c = threadIdx.x;
    float mn = sum[c] * invB;
    float v = sumsq[c] * invB - mn * mn;
    float sc = gma[c] * rsqrtf(v + EPS);
    float sh = bta[c] - mn * sc;
    hs[c] = a_prev[g * 128 + c] * sc + sh;
    __syncthreads();
    float z = b[c];
#pragma unroll 8
    for (int k = 0; k < 128; ++k) z = fmaf(hs[k], W[k * 128 + c], z);
    if (do_leaky) {
        z = leaky(z);
        a_out[g * 128 + c] = z;
        atomicAdd(&sum_out[c], z);
        atomicAdd(&sumsq_out[c], z * z);
    } else {
        a_out[g * 128 + c] = z;
    }
}

extern "C" void kernel_launch(void* const* d_in, const int* in_sizes, int n_in,
                              void* d_out, int out_size, void* d_ws, size_t ws_size,
                              hipStream_t stream) {
    const float* x    = (const float*)d_in[0];
    const int*   ei   = (const int*)d_in[1];
    const float* ea   = (const float*)d_in[2];
    const int*   batch= (const int*)d_in[4];
    const float* W1a  = (const float*)d_in[5];
    const float* b1a  = (const float*)d_in[6];
    const float* g1a  = (const float*)d_in[7];
    const float* be1a = (const float*)d_in[8];
    const float* W2a  = (const float*)d_in[9];
    const float* b2a  = (const float*)d_in[10];
    const float* W1b  = (const float*)d_in[11];
    const float* b1b  = (const float*)d_in[12];
    const float* g1b  = (const float*)d_in[13];
    const float* be1b = (const float*)d_in[14];
    const float* W2b  = (const float*)d_in[15];
    const float* b2b  = (const float*)d_in[16];
    const float* g2b  = (const float*)d_in[17];
    const float* be2b = (const float*)d_in[18];
    const float* W3b  = (const float*)d_in[19];
    const float* b3b  = (const float*)d_in[20];

    const int N = in_sizes[0] / 64;
    const int E = in_sizes[1] / 2;
    const int B = in_sizes[3];

    char* ws = (char*)d_ws;
    size_t off = 0;
    auto alloc = [&](size_t bytes) -> char* {
        char* p = ws + off;
        off = (off + bytes + 255) & ~(size_t)255;
        return p;
    };
    // ---- zeroed region (one memset) ----
    int*   counts = (int*)alloc((size_t)B * 4);
    float* Sg     = (float*)alloc((size_t)B * 128 * 4);
    float* Qg     = (float*)alloc((size_t)B * 128 * 4);
    float* sum1   = (float*)alloc(128 * 4);
    float* sumsq1 = (float*)alloc(128 * 4);
    float* sum2   = (float*)alloc(128 * 4);
    float* sumsq2 = (float*)alloc(128 * 4);
    float* Stot   = (float*)alloc(128 * 4);
    float* Qtot   = (float*)alloc(128 * 4);
    size_t zbytes = off;
    // ---- non-zeroed scratch ----
    float* u       = (float*)alloc((size_t)N * 128 * 4);
    int*   gdst    = (int*)alloc((size_t)E * 4);
    int*   perm    = (int*)alloc((size_t)E * 4);
    int*   edge_off= (int*)alloc((size_t)(B + 1) * 4);
    int*   cursor  = (int*)alloc((size_t)B * 4);
    int*   node_off= (int*)alloc((size_t)(B + 1) * 4);
    float* gx      = (float*)alloc((size_t)B * 64 * 4);
    float* a1      = (float*)alloc((size_t)B * 128 * 4);
    float* a2      = (float*)alloc((size_t)B * 128 * 4);
    float* scale_a = (float*)alloc(128 * 4);
    float* shift_a = (float*)alloc(128 * 4);
    (void)ws_size;
    (void)n_in;

    hipMemsetAsync(ws, 0, zbytes, stream);

    k_u<<<dim3((N + 63) / 64), dim3(128), 0, stream>>>(x, W1a, b1a, u, N);
    k_hist<<<dim3((E + 4095) / 4096), dim3(256), 0, stream>>>(ei, batch, gdst, counts, E);
    k_nodeoff<<<dim3((N + 255) / 256), dim3(256), 0, stream>>>(batch, node_off, N, B);
    k_scan<<<dim3(1), dim3(1024), 0, stream>>>(counts, edge_off, cursor, B);
    k_scat<<<dim3((E + 4095) / 4096), dim3(256), 0, stream>>>(gdst, cursor, perm, E);
    k_gx<<<dim3(B), dim3(64), 0, stream>>>(x, node_off, gx, B);

    const int CH = 8;
    k_edges<<<dim3(B, CH), dim3(256), 0, stream>>>(ea, u, ei, perm, edge_off, W1a,
                                                   Sg, Qg, CH);

    k_stats_part<<<dim3(25), dim3(128), 0, stream>>>(Sg, Qg, Stot, Qtot, B);
    k_stats_fin<<<dim3(1), dim3(128), 0, stream>>>(Stot, Qtot, g1a, be1a, scale_a,
                                                   shift_a, 1.0f / (float)E);
    k_g1<<<dim3(B), dim3(128), 0, stream>>>(Sg, gx, edge_off, scale_a, shift_a, W2a,
                                            b2a, W1b, b1b, a1, sum1, sumsq1);
    k_bn_lin<<<dim3(B), dim3(128), 0, stream>>>(a1, sum1, sumsq1, g1b, be1b, W2b,
                                                b2b, a2, sum2, sumsq2,
                                                1.0f / (float)B, 1);
    k_bn_lin<<<dim3(B), dim3(128), 0, stream>>>(a2, sum2, sumsq2, g2b, be2b, W3b,
                                                b3b, (float*)d_out, nullptr, nullptr,
                                                1.0f / (float)B, 0);
}